// Round 1
// baseline (211.993 us; speedup 1.0000x reference)
//
#include <hip/hip_runtime.h>

#define TM 64
#define TN 64
#define DK 64
#define PADF 4   // pad floats per LDS row: stride 68 floats = 272 B (16B aligned, bank-safe)

__global__ __launch_bounds__(256) void lap_tile_kernel(
    const float* __restrict__ X, float* __restrict__ out,
    float* __restrict__ deg, int N)
{
    const int b  = blockIdx.z;
    const int m0 = blockIdx.y * TM;
    const int n0 = blockIdx.x * TN;
    const int tid = threadIdx.x;

    __shared__ float As[TM][DK + PADF];
    __shared__ float Bs[TN][DK + PADF];

    const float* Xb = X + (size_t)b * N * DK;

    // Stage A tile (rows m0..m0+63, all 64 features) and B tile (rows n0..).
    // 4096 floats each = 1024 float4 loads; 256 threads x 4 iterations.
    {
        const float4* srcA = reinterpret_cast<const float4*>(Xb + (size_t)m0 * DK);
        const float4* srcB = reinterpret_cast<const float4*>(Xb + (size_t)n0 * DK);
#pragma unroll
        for (int it = 0; it < 4; ++it) {
            int idx = tid + it * 256;   // 0..1023
            int r = idx >> 4;           // row 0..63
            int q = idx & 15;           // float4 index within row
            float4 va = srcA[r * 16 + q];
            float4 vb = srcB[r * 16 + q];
            *reinterpret_cast<float4*>(&As[r][q * 4]) = va;
            *reinterpret_cast<float4*>(&Bs[r][q * 4]) = vb;
        }
    }
    __syncthreads();

    const int tx = tid & 15;   // col group 0..15
    const int ty = tid >> 4;   // row group 0..15

    float acc[4][4] = {};
#pragma unroll
    for (int k = 0; k < DK; k += 4) {
        float4 a[4], bb[4];
#pragma unroll
        for (int i = 0; i < 4; ++i)
            a[i] = *reinterpret_cast<const float4*>(&As[ty * 4 + i][k]);
#pragma unroll
        for (int j = 0; j < 4; ++j)
            bb[j] = *reinterpret_cast<const float4*>(&Bs[tx * 4 + j][k]);
#pragma unroll
        for (int i = 0; i < 4; ++i)
#pragma unroll
            for (int j = 0; j < 4; ++j) {
                acc[i][j] += a[i].x * bb[j].x + a[i].y * bb[j].y
                           + a[i].z * bb[j].z + a[i].w * bb[j].w;
            }
    }

    // Epilogue: w = 1.0 if d^2>=0.95, 0.5 if d^2>=0.5, else 0; diag -> 0.
    // out = -w (diagonal fixed up by diag_kernel); rowsum accumulates degree.
    float rowsum[4] = {0.f, 0.f, 0.f, 0.f};
    float* outb = out + (size_t)b * N * N;
#pragma unroll
    for (int i = 0; i < 4; ++i) {
        const int gr = m0 + ty * 4 + i;
        float w[4];
#pragma unroll
        for (int j = 0; j < 4; ++j) {
            const int gc = n0 + tx * 4 + j;
            const float d = acc[i][j];
            const float fid = d * d;
            float wt = (fid >= 0.95f) ? 1.0f : ((fid >= 0.5f) ? 0.5f : 0.0f);
            if (gr == gc) wt = 0.0f;
            rowsum[i] += wt;
            w[j] = -wt;
        }
        float4 st = {w[0], w[1], w[2], w[3]};
        *reinterpret_cast<float4*>(&outb[(size_t)gr * N + (n0 + tx * 4)]) = st;
    }

    // Reduce rowsum across the 16 tx lanes (contiguous within the wave),
    // then one atomicAdd per row per block.
#pragma unroll
    for (int i = 0; i < 4; ++i) {
        float s = rowsum[i];
        s += __shfl_xor(s, 1, 64);
        s += __shfl_xor(s, 2, 64);
        s += __shfl_xor(s, 4, 64);
        s += __shfl_xor(s, 8, 64);
        if (tx == 0) atomicAdd(&deg[(size_t)b * N + m0 + ty * 4 + i], s);
    }
}

__global__ __launch_bounds__(256) void diag_kernel(
    const float* __restrict__ deg, float* __restrict__ out, int N)
{
    const int idx = blockIdx.x * blockDim.x + threadIdx.x;  // b*N + i
    const int b = idx / N;
    const int i = idx - b * N;
    out[(size_t)b * N * N + (size_t)i * N + i] = deg[idx];
}

extern "C" void kernel_launch(void* const* d_in, const int* in_sizes, int n_in,
                              void* d_out, int out_size, void* d_ws, size_t ws_size,
                              hipStream_t stream) {
    const float* X = (const float*)d_in[0];
    float* out = (float*)d_out;
    float* deg = (float*)d_ws;

    const int B = 8;
    const int D = 64;
    const int N = in_sizes[0] / (B * D);   // 2048

    hipMemsetAsync(deg, 0, (size_t)B * N * sizeof(float), stream);

    dim3 grid(N / TN, N / TM, B);
    lap_tile_kernel<<<grid, dim3(256), 0, stream>>>(X, out, deg, N);
    diag_kernel<<<(B * N + 255) / 256, dim3(256), 0, stream>>>(deg, out, N);
}

// Round 2
// 46.583 us; speedup vs baseline: 4.5508x; 4.5508x over previous
//
#include <hip/hip_runtime.h>

typedef __attribute__((ext_vector_type(8))) __bf16 bf16x8;
typedef __attribute__((ext_vector_type(4))) __bf16 bf16x4;
typedef __attribute__((ext_vector_type(4))) float f32x4;

#define BT 128          // block tile (rows and cols)
#define LDST 72         // LDS row stride in bf16 elements (64 + 8 pad -> 144 B, 2-way max)

__global__ __launch_bounds__(256) void lap_mfma_kernel(
    const float* __restrict__ X, float* __restrict__ out,
    float* __restrict__ deg, int N)
{
    const int b  = blockIdx.z;
    const int bm = blockIdx.x;      // A-panel (output cols after transposed store)
    const int bn = blockIdx.y;      // B-panel (output rows after transposed store)
    const int tid = threadIdx.x;

    __shared__ __align__(16) unsigned short As[BT * LDST];
    __shared__ __align__(16) unsigned short Bs[BT * LDST];

    const float* Xb = X + (size_t)b * N * 64;

    // ---- Stage: global fp32 -> bf16 LDS, 128 rows x 64 feats per tile ----
    {
        const float4* srcA = reinterpret_cast<const float4*>(Xb + (size_t)(bm * BT) * 64);
        const float4* srcB = reinterpret_cast<const float4*>(Xb + (size_t)(bn * BT) * 64);
#pragma unroll
        for (int it = 0; it < 8; ++it) {
            int idx = tid + it * 256;          // 0..2047 ; 16 float4 per row
            int r = idx >> 4;
            int q = idx & 15;
            float4 va = srcA[idx];
            float4 vb = srcB[idx];
            bf16x4 ha = { (__bf16)va.x, (__bf16)va.y, (__bf16)va.z, (__bf16)va.w };
            bf16x4 hb = { (__bf16)vb.x, (__bf16)vb.y, (__bf16)vb.z, (__bf16)vb.w };
            *reinterpret_cast<bf16x4*>(&As[r * LDST + q * 4]) = ha;
            *reinterpret_cast<bf16x4*>(&Bs[r * LDST + q * 4]) = hb;
        }
    }
    __syncthreads();

    // ---- Compute: each wave -> 64x64 tile via 4x4 fragments of 16x16x32 ----
    const int lane = tid & 63;
    const int wave = tid >> 6;
    const int t = lane & 15;        // fragment row/col within 16
    const int g = lane >> 4;        // k-group (and C/D row group)
    const int wr = wave >> 1;       // wave row 0..1
    const int wc = wave & 1;        // wave col 0..1

    f32x4 acc[4][4] = {};

#pragma unroll
    for (int ks = 0; ks < 2; ++ks) {
        const int koff = ks * 32 + g * 8;
        bf16x8 a[4], bb[4];
#pragma unroll
        for (int fi = 0; fi < 4; ++fi)
            a[fi] = *reinterpret_cast<const bf16x8*>(&As[(wr * 64 + 16 * fi + t) * LDST + koff]);
#pragma unroll
        for (int fj = 0; fj < 4; ++fj)
            bb[fj] = *reinterpret_cast<const bf16x8*>(&Bs[(wc * 64 + 16 * fj + t) * LDST + koff]);
#pragma unroll
        for (int fi = 0; fi < 4; ++fi)
#pragma unroll
            for (int fj = 0; fj < 4; ++fj)
                acc[fi][fj] = __builtin_amdgcn_mfma_f32_16x16x32_bf16(
                    a[fi], bb[fj], acc[fi][fj], 0, 0, 0);
    }

    // ---- Epilogue: threshold map; transposed store (L symmetric) ----
    // acc[fi][fj][reg] = C[R0+16*fi+4*g+reg][C0+16*fj+t]; store at out[col][row].
    const int R0 = bm * BT + wr * 64;
    const int C0 = bn * BT + wc * 64;
    float* outb = out + (size_t)b * N * N;

#pragma unroll
    for (int fj = 0; fj < 4; ++fj) {
        const int orow = C0 + 16 * fj + t;    // output row
        float rs = 0.f;
#pragma unroll
        for (int fi = 0; fi < 4; ++fi) {
            const int ocol0 = R0 + 16 * fi + 4 * g;
            float w[4];
#pragma unroll
            for (int r = 0; r < 4; ++r) {
                const float v = acc[fi][fj][r];
                const float fid = v * v;
                float wt = (fid >= 0.95f) ? 1.0f : ((fid >= 0.5f) ? 0.5f : 0.0f);
                if (ocol0 + r == orow) wt = 0.0f;   // diagonal
                rs += wt;
                w[r] = -wt;
            }
            float4 st = { w[0], w[1], w[2], w[3] };
            *reinterpret_cast<float4*>(&outb[(size_t)orow * N + ocol0]) = st;
        }
        // reduce the 64-col partial degree across the 4 g-groups
        rs += __shfl_xor(rs, 16, 64);
        rs += __shfl_xor(rs, 32, 64);
        if (g == 0) atomicAdd(&deg[(size_t)b * N + orow], rs);
    }
}

__global__ __launch_bounds__(256) void diag_kernel(
    const float* __restrict__ deg, float* __restrict__ out, int N)
{
    const int idx = blockIdx.x * blockDim.x + threadIdx.x;  // b*N + i
    const int b = idx / N;
    const int i = idx - b * N;
    out[(size_t)b * N * N + (size_t)i * N + i] = deg[idx];
}

extern "C" void kernel_launch(void* const* d_in, const int* in_sizes, int n_in,
                              void* d_out, int out_size, void* d_ws, size_t ws_size,
                              hipStream_t stream) {
    const float* X = (const float*)d_in[0];
    float* out = (float*)d_out;
    float* deg = (float*)d_ws;

    const int B = 8;
    const int D = 64;
    const int N = in_sizes[0] / (B * D);   // 2048

    hipMemsetAsync(deg, 0, (size_t)B * N * sizeof(float), stream);

    dim3 grid(N / BT, N / BT, B);
    lap_mfma_kernel<<<grid, dim3(256), 0, stream>>>(X, out, deg, N);
    diag_kernel<<<(B * N + 255) / 256, dim3(256), 0, stream>>>(deg, out, N);
}

// Round 7
// 34.959 us; speedup vs baseline: 6.0641x; 1.3325x over previous
//
#include <hip/hip_runtime.h>

typedef __attribute__((ext_vector_type(8))) __bf16 bf16x8;
typedef __attribute__((ext_vector_type(4))) __bf16 bf16x4;
typedef __attribute__((ext_vector_type(4))) float f32x4;

#define LDST 72   // LDS row stride in bf16 (64 + 8 pad -> 144 B, max 2-way conflict = free)

// One block = one 32-row strip x ALL columns of one batch.
// Grid: (N/32, B). 256 threads = 4 waves; wave w owns a 32-col quarter of each 128-col tile.
__global__ __launch_bounds__(256) void lap_strip_kernel(
    const float* __restrict__ X, float* __restrict__ out, int N)
{
    const int b      = blockIdx.y;
    const int strip0 = blockIdx.x * 32;
    const int tid  = threadIdx.x;
    const int lane = tid & 63;
    const int w    = tid >> 6;     // wave id 0..3
    const int t    = lane & 15;
    const int g    = lane >> 4;

    __shared__ __align__(16) unsigned short As[2][128 * LDST];  // col-panel double buffer
    __shared__ __align__(16) unsigned short Bs[32 * LDST];      // strip (loop-invariant)
    __shared__ float deg_part[4][32];

    const float* Xb   = X   + (size_t)b * N * 64;
    float*       outb = out + (size_t)b * N * N;

    // ---- stage strip rows (B operand): 32 x 64, fp32 -> bf16 ----
    {
        const float4* src = reinterpret_cast<const float4*>(Xb + (size_t)strip0 * 64);
#pragma unroll
        for (int it = 0; it < 2; ++it) {
            int idx = tid + it * 256;            // 0..511 ; 16 float4 per row
            int r = idx >> 4, q = idx & 15;
            float4 v = src[idx];
            bf16x4 h = {(__bf16)v.x, (__bf16)v.y, (__bf16)v.z, (__bf16)v.w};
            *reinterpret_cast<bf16x4*>(&Bs[r * LDST + q * 4]) = h;
        }
    }

    // ---- stage col-panel 0 into As[0] ----
    float4 pre[8];
    {
        const float4* src = reinterpret_cast<const float4*>(Xb);
#pragma unroll
        for (int it = 0; it < 8; ++it) pre[it] = src[tid + it * 256];
#pragma unroll
        for (int it = 0; it < 8; ++it) {
            int idx = tid + it * 256;            // 0..2047 ; 128 rows x 16 float4
            int r = idx >> 4, q = idx & 15;
            float4 v = pre[it];
            bf16x4 h = {(__bf16)v.x, (__bf16)v.y, (__bf16)v.z, (__bf16)v.w};
            *reinterpret_cast<bf16x4*>(&As[0][r * LDST + q * 4]) = h;
        }
    }
    __syncthreads();

    // strip fragments are loop-invariant: load once
    bf16x8 bfrag[2][2];   // [ks][fj]
#pragma unroll
    for (int ks = 0; ks < 2; ++ks)
#pragma unroll
        for (int fj = 0; fj < 2; ++fj)
            bfrag[ks][fj] = *reinterpret_cast<const bf16x8*>(
                &Bs[(16 * fj + t) * LDST + ks * 32 + g * 8]);

    float rs[2] = {0.f, 0.f};
    int cur = 0;
    const int nct = N >> 7;            // 16 column tiles of 128
    const int diag_ct = strip0 >> 7;   // the tile containing this strip's diagonal

    for (int ct = 0; ct < nct; ++ct) {
        // T14: issue next panel's global loads before compute (latency hides under MFMA+stores)
        if (ct + 1 < nct) {
            const float4* src = reinterpret_cast<const float4*>(Xb + (size_t)(ct + 1) * 128 * 64);
#pragma unroll
            for (int it = 0; it < 8; ++it) pre[it] = src[tid + it * 256];
        }

        // ---- compute 32 (strip) x 128 (cols): 2x2 fragments x 2 k-steps ----
        f32x4 acc[2][2] = {};
#pragma unroll
        for (int ks = 0; ks < 2; ++ks) {
            const int koff = ks * 32 + g * 8;
            bf16x8 a[2];
#pragma unroll
            for (int fi = 0; fi < 2; ++fi)
                a[fi] = *reinterpret_cast<const bf16x8*>(
                    &As[cur][(32 * w + 16 * fi + t) * LDST + koff]);
#pragma unroll
            for (int fi = 0; fi < 2; ++fi)
#pragma unroll
                for (int fj = 0; fj < 2; ++fj)
                    acc[fi][fj] = __builtin_amdgcn_mfma_f32_16x16x32_bf16(
                        a[fi], bfrag[ks][fj], acc[fi][fj], 0, 0, 0);
        }

        // ---- epilogue: |d| thresholds; transposed store -> contiguous float4 ----
        const bool has_diag = (ct == diag_ct);
#pragma unroll
        for (int fj = 0; fj < 2; ++fj) {
            const int orow = strip0 + 16 * fj + t;       // output row (strip side)
#pragma unroll
            for (int fi = 0; fi < 2; ++fi) {
                const int ocol0 = ct * 128 + 32 * w + 16 * fi + 4 * g;
                float wv[4];
#pragma unroll
                for (int r = 0; r < 4; ++r) {
                    const float d = acc[fi][fj][r];
                    float wt = (fabsf(d) >= 0.97467943f) ? 1.0f
                             : ((fabsf(d) >= 0.70710678f) ? 0.5f : 0.0f);
                    if (has_diag && (ocol0 + r == orow)) wt = 0.0f;
                    rs[fj] += wt;
                    wv[r] = -wt;
                }
                f32x4 st = {wv[0], wv[1], wv[2], wv[3]};
                f32x4* dst = reinterpret_cast<f32x4*>(&outb[(size_t)orow * N + ocol0]);
                if (has_diag) *dst = st;                       // normal store (diag overwritten later)
                else __builtin_nontemporal_store(st, dst);     // streaming, never re-read
            }
        }

        // ---- write next panel into the other buffer ----
        if (ct + 1 < nct) {
#pragma unroll
            for (int it = 0; it < 8; ++it) {
                int idx = tid + it * 256;
                int r = idx >> 4, q = idx & 15;
                float4 v = pre[it];
                bf16x4 h = {(__bf16)v.x, (__bf16)v.y, (__bf16)v.z, (__bf16)v.w};
                *reinterpret_cast<bf16x4*>(&As[cur ^ 1][r * LDST + q * 4]) = h;
            }
        }
        __syncthreads();
        cur ^= 1;
    }

    // ---- degree: reduce over g (cols within wave), then across 4 waves via LDS ----
    rs[0] += __shfl_xor(rs[0], 16, 64); rs[0] += __shfl_xor(rs[0], 32, 64);
    rs[1] += __shfl_xor(rs[1], 16, 64); rs[1] += __shfl_xor(rs[1], 32, 64);
    if (g == 0) { deg_part[w][t] = rs[0]; deg_part[w][16 + t] = rs[1]; }
    __syncthreads();
    if (tid < 32) {
        float d = deg_part[0][tid] + deg_part[1][tid] + deg_part[2][tid] + deg_part[3][tid];
        const int rr = strip0 + tid;
        outb[(size_t)rr * N + rr] = d;   // diagonal = degree
    }
}

extern "C" void kernel_launch(void* const* d_in, const int* in_sizes, int n_in,
                              void* d_out, int out_size, void* d_ws, size_t ws_size,
                              hipStream_t stream) {
    const float* X = (const float*)d_in[0];
    float* out = (float*)d_out;

    const int B = 8;
    const int D = 64;
    const int N = in_sizes[0] / (B * D);   // 2048

    dim3 grid(N / 32, B);
    lap_strip_kernel<<<grid, dim3(256), 0, stream>>>(X, out, N);
}

// Round 8
// 34.320 us; speedup vs baseline: 6.1770x; 1.0186x over previous
//
#include <hip/hip_runtime.h>

typedef __attribute__((ext_vector_type(8))) __bf16 bf16x8;
typedef __attribute__((ext_vector_type(4))) __bf16 bf16x4;
typedef __attribute__((ext_vector_type(4))) float f32x4;

#define LDST 72   // LDS row stride in bf16 (64 + 8 pad -> 144 B, max 2-way conflict = free)

// Barrier that only drains this wave's LDS ops (lgkmcnt), NOT vmem stores.
// Safe with double-buffered LDS: reads hit buf[cur], writes hit buf[cur^1].
__device__ __forceinline__ void lds_barrier() {
    asm volatile("s_waitcnt lgkmcnt(0)" ::: "memory");
    __builtin_amdgcn_s_barrier();
    __builtin_amdgcn_sched_barrier(0);
}
// Full drain (stores too) — used once before the diagonal overwrite.
__device__ __forceinline__ void full_barrier() {
    asm volatile("s_waitcnt vmcnt(0) lgkmcnt(0)" ::: "memory");
    __builtin_amdgcn_s_barrier();
    __builtin_amdgcn_sched_barrier(0);
}

// One block = one 32-row strip x ALL columns of one batch. 512 threads = 8 waves;
// wave w owns 16 panel-cols of each 128-col tile. Grid: flat 512 blocks,
// batch = id & 7 (one batch per XCD for L2 panel reuse).
__global__ __launch_bounds__(512) void lap_strip_kernel(
    const float* __restrict__ X, float* __restrict__ out, int N)
{
    const int flat   = blockIdx.x;
    const int b      = flat & 7;
    const int strip0 = (flat >> 3) * 32;
    const int tid  = threadIdx.x;     // 0..511
    const int lane = tid & 63;
    const int w    = tid >> 6;        // wave 0..7
    const int t    = lane & 15;
    const int g    = lane >> 4;

    __shared__ __align__(16) unsigned short As[2][128 * LDST];  // col-panel double buffer
    __shared__ __align__(16) unsigned short Bs[32 * LDST];      // strip (loop-invariant)
    __shared__ float deg_part[8][32];

    const float* Xb   = X   + (size_t)b * N * 64;
    float*       outb = out + (size_t)b * N * N;

    // ---- stage strip rows: 32 x 64 fp32 -> bf16 (512 float4, one per thread) ----
    {
        const float4* src = reinterpret_cast<const float4*>(Xb + (size_t)strip0 * 64);
        int r = tid >> 4, q = tid & 15;
        float4 v = src[tid];
        bf16x4 h = {(__bf16)v.x, (__bf16)v.y, (__bf16)v.z, (__bf16)v.w};
        *reinterpret_cast<bf16x4*>(&Bs[r * LDST + q * 4]) = h;
    }

    // ---- stage col-panel 0 into As[0] (2048 float4 = 4 per thread) ----
    float4 pre[4];
    {
        const float4* src = reinterpret_cast<const float4*>(Xb);
#pragma unroll
        for (int it = 0; it < 4; ++it) pre[it] = src[tid + it * 512];
#pragma unroll
        for (int it = 0; it < 4; ++it) {
            int idx = tid + it * 512;
            int r = idx >> 4, q = idx & 15;
            float4 v = pre[it];
            bf16x4 h = {(__bf16)v.x, (__bf16)v.y, (__bf16)v.z, (__bf16)v.w};
            *reinterpret_cast<bf16x4*>(&As[0][r * LDST + q * 4]) = h;
        }
    }
    lds_barrier();

    // strip fragments are loop-invariant: load once
    bf16x8 bfrag[2][2];   // [ks][fj]
#pragma unroll
    for (int ks = 0; ks < 2; ++ks)
#pragma unroll
        for (int fj = 0; fj < 2; ++fj)
            bfrag[ks][fj] = *reinterpret_cast<const bf16x8*>(
                &Bs[(16 * fj + t) * LDST + ks * 32 + g * 8]);

    float rs[2] = {0.f, 0.f};
    int cur = 0;
    const int nct = N >> 7;            // 16 column tiles of 128
    const int diag_ct = strip0 >> 7;

    for (int ct = 0; ct < nct; ++ct) {
        // prefetch next panel into regs (hides HBM latency under MFMA+stores)
        if (ct + 1 < nct) {
            const float4* src = reinterpret_cast<const float4*>(Xb + (size_t)(ct + 1) * 128 * 64);
#pragma unroll
            for (int it = 0; it < 4; ++it) pre[it] = src[tid + it * 512];
        }

        // ---- compute: wave w -> panel rows [16w,16w+16) x strip 32 rows ----
        f32x4 acc[2] = {};   // [fj]
#pragma unroll
        for (int ks = 0; ks < 2; ++ks) {
            const int koff = ks * 32 + g * 8;
            bf16x8 a = *reinterpret_cast<const bf16x8*>(
                &As[cur][(16 * w + t) * LDST + koff]);
#pragma unroll
            for (int fj = 0; fj < 2; ++fj)
                acc[fj] = __builtin_amdgcn_mfma_f32_16x16x32_bf16(
                    a, bfrag[ks][fj], acc[fj], 0, 0, 0);
        }

        // ---- epilogue: |d| thresholds; transposed store -> contiguous f32x4 ----
        const bool has_diag = (ct == diag_ct);
#pragma unroll
        for (int fj = 0; fj < 2; ++fj) {
            const int orow  = strip0 + 16 * fj + t;          // output row (strip side)
            const int ocol0 = ct * 128 + 16 * w + 4 * g;     // output col base (panel side)
            float wv[4];
#pragma unroll
            for (int r = 0; r < 4; ++r) {
                const float d = acc[fj][r];
                float wt = (fabsf(d) >= 0.97467943f) ? 1.0f
                         : ((fabsf(d) >= 0.70710678f) ? 0.5f : 0.0f);
                if (has_diag && (ocol0 + r == orow)) wt = 0.0f;
                rs[fj] += wt;
                wv[r] = -wt;
            }
            f32x4 st = {wv[0], wv[1], wv[2], wv[3]};
            f32x4* dst = reinterpret_cast<f32x4*>(&outb[(size_t)orow * N + ocol0]);
            if (has_diag) *dst = st;                       // normal store (diag line)
            else __builtin_nontemporal_store(st, dst);     // streaming, never re-read
        }

        // ---- write next panel into the other buffer ----
        if (ct + 1 < nct) {
#pragma unroll
            for (int it = 0; it < 4; ++it) {
                int idx = tid + it * 512;
                int r = idx >> 4, q = idx & 15;
                float4 v = pre[it];
                bf16x4 h = {(__bf16)v.x, (__bf16)v.y, (__bf16)v.z, (__bf16)v.w};
                *reinterpret_cast<bf16x4*>(&As[cur ^ 1][r * LDST + q * 4]) = h;
            }
        }
        lds_barrier();
        cur ^= 1;
    }

    // ---- degree: reduce over g via shfl, across 8 waves via LDS ----
    rs[0] += __shfl_xor(rs[0], 16, 64); rs[0] += __shfl_xor(rs[0], 32, 64);
    rs[1] += __shfl_xor(rs[1], 16, 64); rs[1] += __shfl_xor(rs[1], 32, 64);
    if (g == 0) { deg_part[w][t] = rs[0]; deg_part[w][16 + t] = rs[1]; }
    full_barrier();   // drains vmem too: the diag-line store must land before overwrite
    if (tid < 32) {
        float d = 0.f;
#pragma unroll
        for (int ww = 0; ww < 8; ++ww) d += deg_part[ww][tid];
        const int rr = strip0 + tid;
        outb[(size_t)rr * N + rr] = d;   // diagonal = degree
    }
}

extern "C" void kernel_launch(void* const* d_in, const int* in_sizes, int n_in,
                              void* d_out, int out_size, void* d_ws, size_t ws_size,
                              hipStream_t stream) {
    const float* X = (const float*)d_in[0];
    float* out = (float*)d_out;

    const int B = 8;
    const int D = 64;
    const int N = in_sizes[0] / (B * D);   // 2048

    dim3 grid((N / 32) * B);               // 512 blocks, batch = id & 7
    lap_strip_kernel<<<grid, dim3(512), 0, stream>>>(X, out, N);
}